// Round 6
// baseline (434.909 us; speedup 1.0000x reference)
//
#include <hip/hip_runtime.h>
#include <hip/hip_bf16.h>

typedef __bf16 bf16x8 __attribute__((ext_vector_type(8)));
typedef float f32x4 __attribute__((ext_vector_type(4)));
using u16 = unsigned short;
using u32 = unsigned int;

__device__ __forceinline__ float bf2f(u16 v) {
    unsigned int u = (unsigned int)v << 16;
    float f; __builtin_memcpy(&f, &u, 4); return f;
}
__device__ __forceinline__ u16 f2bf(float f) {
    unsigned int u; __builtin_memcpy(&u, &f, 4);
    u += 0x7FFFu + ((u >> 16) & 1u);   // RNE (finite data only)
    return (u16)(u >> 16);
}

// ---------------------------------------------------------------------------
// Bulk fp32 -> bf16 conversion, 9 segments, 8 elems/thread.
// ---------------------------------------------------------------------------
struct Cvt9 {
    const float* src[9];
    u16* dst[9];
    int end[9];      // cumulative chunk ends (chunks of 8 elems)
};
__global__ __launch_bounds__(256) void cvt_all(Cvt9 d, int total)
{
    int c = blockIdx.x * 256 + threadIdx.x;
    if (c >= total) return;
    int seg = 0;
    while (c >= d.end[seg]) ++seg;
    int local = c - (seg ? d.end[seg - 1] : 0);
    const float* s = d.src[seg] + (size_t)local * 8;
    float4 f0 = *(const float4*)s;
    float4 f1 = *(const float4*)(s + 4);
    u16 tmp[8] = { f2bf(f0.x), f2bf(f0.y), f2bf(f0.z), f2bf(f0.w),
                   f2bf(f1.x), f2bf(f1.y), f2bf(f1.z), f2bf(f1.w) };
    *(uint4*)(d.dst[seg] + (size_t)local * 8) = *(const uint4*)tmp;
}

// ---------------------------------------------------------------------------
// Bias concatenation (fp32 copy, 7 segments).
// ---------------------------------------------------------------------------
struct Cpy7 {
    const float* src[7];
    float* dst[7];
    int end[7];
};
__global__ __launch_bounds__(256) void copy_f32(Cpy7 d, int total)
{
    int c = blockIdx.x * 256 + threadIdx.x;
    if (c >= total) return;
    int seg = 0;
    while (c >= d.end[seg]) ++seg;
    int local = c - (seg ? d.end[seg - 1] : 0);
    d.dst[seg][local] = d.src[seg][local];
}

// ---------------------------------------------------------------------------
// Pure-bf16 C = A @ B^T + bias GEMM, two independent "halves" selected by
// blockIdx.y < ysplit.  v5:
//  * 3-buffer LDS pipeline (BK=32, 3 x 16 KB = 48 KB, 3 WG/CU): tile t+2 is
//    staged while computing t; steady-state s_waitcnt vmcnt(8) gives every
//    tile's global_load_lds TWO compute phases of latency cover (T3/T4).
//  * swapped-operand MFMA: acc[i][j] = mfma(bfr[j], af[i], acc) so each lane
//    holds 4 CONSECUTIVE COLUMNS of one C row -> vectorized epilogue
//    (uint2 bf16 / float4 f32 stores, float4 bias loads), 16 stores not 64.
// Swizzle: stored 16B chunk agc = slot ^ ((sub>>1)&3) per 16-row group;
// fragment b128 reads unswizzle with (quad ^ sfr).  128x128 tile, 4 waves,
// 4x4 grid of 16x16x32 bf16 MFMA/wave.  M mult of 128; K mult of 32 (>=64);
// N mult of 4; epilogue guards col < N.
// ---------------------------------------------------------------------------
template<bool CF>
__global__ __launch_bounds__(256) void gemm_v5(
    const u16* __restrict__ A0, const u16* __restrict__ B0, void* __restrict__ C0, const float* __restrict__ e0,
    const u16* __restrict__ A1, const u16* __restrict__ B1, void* __restrict__ C1, const float* __restrict__ e1,
    int ysplit, int lda, int ldb, int ldc, int N, int K)
{
    __shared__ __align__(16) u16 As[3][128 * 32];
    __shared__ __align__(16) u16 Bs[3][128 * 32];

    const int t = threadIdx.x;
    const int lane = t & 63;
    const int w = t >> 6;
    const int wm = w >> 1, wn = w & 1;
    const int l16 = lane & 15, quad = lane >> 4;
    const int m0 = blockIdx.x * 128;

    const u16* A; const u16* B; void* Cv; const float* bias; int yl;
    if ((int)blockIdx.y < ysplit) { A = A0; B = B0; Cv = C0; bias = e0; yl = blockIdx.y; }
    else                          { A = A1; B = B1; Cv = C1; bias = e1; yl = blockIdx.y - ysplit; }
    const int n0 = yl * 128;

    const int sub  = lane >> 2;                 // 0..15: row within 16-row chunk
    const int slot = lane & 3;                  // 16B slot within 64B row
    const int agc  = slot ^ ((sub >> 1) & 3);   // swizzled global chunk
    const int sfr  = (l16 >> 1) & 3;            // fragment-read unswizzle

    f32x4 acc[4][4];
#pragma unroll
    for (int i = 0; i < 4; ++i)
#pragma unroll
        for (int j = 0; j < 4; ++j) acc[i][j] = (f32x4){0.f, 0.f, 0.f, 0.f};

    auto STAGE = [&](int buf, int k0) {
#pragma unroll
        for (int c = 0; c < 2; ++c) {
            const int rr = w * 32 + c * 16;
            const u16* ga = A + (size_t)(m0 + rr + sub) * lda + k0 + agc * 8;
            __builtin_amdgcn_global_load_lds(
                (const __attribute__((address_space(1))) u32*)ga,
                (__attribute__((address_space(3))) u32*)&As[buf][rr * 32], 16, 0, 0);
            const u16* gb = B + (size_t)(n0 + rr + sub) * ldb + k0 + agc * 8;
            __builtin_amdgcn_global_load_lds(
                (const __attribute__((address_space(1))) u32*)gb,
                (__attribute__((address_space(3))) u32*)&Bs[buf][rr * 32], 16, 0, 0);
        }
    };

    const int nt = K >> 5;
    STAGE(0, 0);
    STAGE(1, 32);
    int cur = 0;
    for (int tt = 0; tt < nt; ++tt) {
        int pre = cur + 2; if (pre >= 3) pre -= 3;
        if (tt + 2 < nt) {
            STAGE(pre, (tt + 2) << 5);
            asm volatile("s_waitcnt vmcnt(8)");   // tile tt's 4 loads landed
        } else if (tt + 1 < nt) {
            asm volatile("s_waitcnt vmcnt(4)");
        } else {
            asm volatile("s_waitcnt vmcnt(0)");
        }
        __builtin_amdgcn_sched_barrier(0);
        __builtin_amdgcn_s_barrier();             // everyone's tile-tt loads landed
        __builtin_amdgcn_sched_barrier(0);

        const u16* Ab = As[cur];
        const u16* Bb = Bs[cur];
        bf16x8 af[4], bfr[4];
#pragma unroll
        for (int i = 0; i < 4; ++i)
            af[i] = *(const bf16x8*)&Ab[(wm * 64 + i * 16 + l16) * 32 + (quad ^ sfr) * 8];
#pragma unroll
        for (int j = 0; j < 4; ++j)
            bfr[j] = *(const bf16x8*)&Bb[(wn * 64 + j * 16 + l16) * 32 + (quad ^ sfr) * 8];
#pragma unroll
        for (int i = 0; i < 4; ++i)
#pragma unroll
            for (int j = 0; j < 4; ++j)
                acc[i][j] = __builtin_amdgcn_mfma_f32_16x16x32_bf16(bfr[j], af[i], acc[i][j], 0, 0, 0);

        __builtin_amdgcn_s_barrier();             // done reading cur -> restageable
        __builtin_amdgcn_sched_barrier(0);
        cur += 1; if (cur >= 3) cur -= 3;
    }

    // Swapped-operand C layout: acc[i][j][r] = C[m0+wm*64+i*16+l16]
    //                                           [n0+wn*64+j*16+quad*4+r]
#pragma unroll
    for (int i = 0; i < 4; ++i) {
        const int row = m0 + wm * 64 + i * 16 + l16;
#pragma unroll
        for (int j = 0; j < 4; ++j) {
            const int colb = n0 + wn * 64 + j * 16 + quad * 4;
            if (colb >= N) continue;
            float4 bv = *(const float4*)&bias[colb];
            float v0 = acc[i][j][0] + bv.x;
            float v1 = acc[i][j][1] + bv.y;
            float v2 = acc[i][j][2] + bv.z;
            float v3 = acc[i][j][3] + bv.w;
            if (CF) {
                float4 out = { v0, v1, v2, v3 };
                *(float4*)((float*)Cv + (size_t)row * ldc + colb) = out;
            } else {
                u16 p[4] = { f2bf(v0), f2bf(v1), f2bf(v2), f2bf(v3) };
                *(uint2*)((u16*)Cv + (size_t)row * ldc + colb) = *(const uint2*)p;
            }
        }
    }
}

// ---------------------------------------------------------------------------
// RoPE in place on bf16 ws buffers (source quirk: cos_pos = sin, sin_pos =
// cos):  out[2i] = x[2i]*sin - x[2i+1]*cos ; out[2i+1] = x[2i+1]*sin +
// x[2i]*cos ;  ang = (row % 512) * 10000^(-i/32).
// ---------------------------------------------------------------------------
__global__ void rope_inplace(u16* __restrict__ buf, int ld, int col0, int ppr, int total)
{
    int idx = blockIdx.x * 256 + threadIdx.x;
    if (idx >= total) return;
    int row = idx / ppr;
    int pi  = idx - row * ppr;
    int grp = pi >> 5;
    int i   = pi & 31;
    int pos = row & 511;
    float theta = __expf(-(float)i * 0.2878231366242558f);  // ln(10000)/32
    float ang = (float)pos * theta;
    float s = sinf(ang), c = cosf(ang);
    size_t base = (size_t)row * ld + col0 + grp * 64 + 2 * i;
    float x0 = bf2f(buf[base]);
    float x1 = bf2f(buf[base + 1]);
    buf[base]     = f2bf(x0 * s - x1 * c);
    buf[base + 1] = f2bf(x1 * s + x0 * c);
}

// ---------------------------------------------------------------------------
// Flash attention (all operands bf16 in ws).  One WG = (b, h, 64-row q tile),
// 4 waves; wave w owns a 16-row q strip.  64-key tiles, online softmax in
// log2 domain.  Q in registers.
// T14 async staging with RAW barriers: __syncthreads() would drain vmcnt(0)
// at the barrier (fence semantics), killing the prefetch; instead use
// __builtin_amdgcn_s_barrier() + explicit lgkmcnt(0) for the ds_write
// visibility, so the kt+1 global loads stay in flight under compute.
// Temporal XCD swizzle (1-D grid): xcd = id&7, qt = (id>>3)&7,
// panel = xcd + 8*(id>>6) -> the 8 qt-sharers of a (b,h) K/V panel run
// back-to-back on ONE XCD (16 panels x 192 KB < 4 MB L2) -> K/V L2-served.
// Vt and Ps keep rotation swizzles (2-way writes):
//   Vt physical key pos = (key + (vd&~7)) & 63
//   Ps physical col     = (col + Rp(quad)) & 63
// Output into o_dst cols 0..1023 (aliases out1's dead c_kv/c_q region; this
// kernel only READS out1 cols 1024..1087, byte-disjoint from the writes).
// ---------------------------------------------------------------------------
__global__ __launch_bounds__(256) void attn_kernel(
    const u16* __restrict__ q_src,   // 8192 x 2048 : [q_c | q_r(roped)]
    const u16* __restrict__ kv_src,  // 8192 x 2048 : [k_c | v_c]
    const u16* __restrict__ kr_src,  // 8192 x 1088 : k_r at col 1024 (roped)
    u16* __restrict__ o_dst, int ldo)
{
    __shared__ __align__(16) u16 Ks[64 * 136];
    __shared__ __align__(16) u16 Vt[64 * 72];   // [vd][key] rotated
    __shared__ __align__(16) u16 Ps[64 * 72];   // [q][key] rotated

    const int t = threadIdx.x;
    const int lane = t & 63;
    const int w = t >> 6;
    const int l16 = lane & 15, quad = lane >> 4;

    const int id   = blockIdx.x;
    const int xcd  = id & 7;
    const int qt   = (id >> 3) & 7;
    const int panel = xcd + ((id >> 6) << 3);   // 0..255
    const int h = panel & 15;
    const int b = panel >> 4;
    const int qrow0 = b * 512 + qt * 64;
    const int krow_base = b * 512;

    // Q fragments straight to registers: wave w owns q rows w*16..w*16+15.
    bf16x8 aq[4];
    {
        const u16* qrow = q_src + (size_t)(qrow0 + w * 16 + l16) * 2048;
#pragma unroll
        for (int ks = 0; ks < 4; ++ks) {
            int col = ks * 32 + quad * 8;
            const u16* src = (col < 64) ? qrow + h * 64 + col
                                        : qrow + 1024 + h * 64 + (col - 64);
            aq[ks] = *(const bf16x8*)src;
        }
    }

    // --- staging geometry (kt-independent) ---
    const int colK = (t & 15) * 8;            // K column chunk (u16)
    const int r0k  = t >> 4;                  // K row 0..15 (+16p)
    const u16* kbase; int kstr;
    if (colK < 64) { kbase = kv_src + h * 64 + colK;        kstr = 2048; }
    else           { kbase = kr_src + 1024 + (colK - 64);   kstr = 1088; }
    u16* kw = &Ks[r0k * 136 + colK];

    const int v00 = (t & 7) * 8;              // vd chunk
    const int r0v = t >> 3;                   // key row 0..31 (+32p)
    const u16* vbase = kv_src + 1024 + h * 64 + v00;
    const int rotA = (r0v + v00) & 63;
    const int rotB = (r0v + 32 + v00) & 63;
    u16* vwA = &Vt[v00 * 72 + rotA];
    u16* vwB = &Vt[v00 * 72 + rotB];

    auto LOADT = [&](int krow0, uint4& K0, uint4& K1, uint4& K2, uint4& K3,
                     uint4& V0, uint4& V1) {
        K0 = *(const uint4*)(kbase + (size_t)(krow0 + r0k     ) * kstr);
        K1 = *(const uint4*)(kbase + (size_t)(krow0 + r0k + 16) * kstr);
        K2 = *(const uint4*)(kbase + (size_t)(krow0 + r0k + 32) * kstr);
        K3 = *(const uint4*)(kbase + (size_t)(krow0 + r0k + 48) * kstr);
        V0 = *(const uint4*)(vbase + (size_t)(krow0 + r0v     ) * 2048);
        V1 = *(const uint4*)(vbase + (size_t)(krow0 + r0v + 32) * 2048);
    };
    auto WRITET = [&](const uint4& K0, const uint4& K1, const uint4& K2, const uint4& K3,
                      const uint4& V0, const uint4& V1) {
        *(uint4*)(kw)            = K0;
        *(uint4*)(kw + 16 * 136) = K1;
        *(uint4*)(kw + 32 * 136) = K2;
        *(uint4*)(kw + 48 * 136) = K3;
        u16 ta[8], tb[8];
        __builtin_memcpy(ta, &V0, 16);
        __builtin_memcpy(tb, &V1, 16);
#pragma unroll
        for (int j2 = 0; j2 < 8; ++j2) { vwA[j2 * 72] = ta[j2]; vwB[j2 * 72] = tb[j2]; }
    };

    float m2[4], l_run[4];                    // m2 in log2 domain
    f32x4 o[4];
#pragma unroll
    for (int r = 0; r < 4; ++r) { m2[r] = -1e30f; l_run[r] = 0.f; }
#pragma unroll
    for (int n = 0; n < 4; ++n) o[n] = (f32x4){0.f, 0.f, 0.f, 0.f};

    const float C = 0.10411756f;              // log2(e)/sqrt(192)
    const int Rp = (64 - (quad << 4)) & 48;          // Ps write rotation
    const int Rr = (64 - ((l16 >> 2) << 4)) & 48;    // Ps read rotation

    uint4 kA0, kA1, kA2, kA3, vA0, vA1;
    uint4 kB0, kB1, kB2, kB3, vB0, vB1;
    LOADT(krow_base, kA0, kA1, kA2, kA3, vA0, vA1);   // kt = 0

    for (int kt = 0; kt < 8; ++kt) {
        // (A) all waves done reading Ks/Vt of previous tile
        __builtin_amdgcn_s_barrier();
        __builtin_amdgcn_sched_barrier(0);
        if ((kt & 1) == 0) {
            WRITET(kA0, kA1, kA2, kA3, vA0, vA1);
            if (kt < 7) LOADT(krow_base + (kt + 1) * 64, kB0, kB1, kB2, kB3, vB0, vB1);
        } else {
            WRITET(kB0, kB1, kB2, kB3, vB0, vB1);
            if (kt < 7) LOADT(krow_base + (kt + 1) * 64, kA0, kA1, kA2, kA3, vA0, vA1);
        }
        asm volatile("s_waitcnt lgkmcnt(0)");     // my ds_writes visible
        __builtin_amdgcn_sched_barrier(0);
        // (B) everyone's ds_writes visible; vmcnt NOT drained -> prefetch flies
        __builtin_amdgcn_s_barrier();
        __builtin_amdgcn_sched_barrier(0);

        // S strip = Q K^T  (16 q rows x 64 keys), contraction d=128, raw scores
        f32x4 s[4];
#pragma unroll
        for (int n = 0; n < 4; ++n) s[n] = (f32x4){0.f, 0.f, 0.f, 0.f};
#pragma unroll
        for (int ks = 0; ks < 4; ++ks) {
#pragma unroll
            for (int n = 0; n < 4; ++n) {
                bf16x8 bk = *(const bf16x8*)&Ks[(n * 16 + l16) * 136 + ks * 32 + quad * 8];
                s[n] = __builtin_amdgcn_mfma_f32_16x16x32_bf16(aq[ks], bk, s[n], 0, 0, 0);
            }
        }

        // online softmax (log2 domain); lane owns rows quad*4+r, cols l16 (+16n)
        float mx[4], alpha[4], rs[4];
#pragma unroll
        for (int r = 0; r < 4; ++r)
            mx[r] = fmaxf(fmaxf(s[0][r], s[1][r]), fmaxf(s[2][r], s[3][r]));
#pragma unroll
        for (int d = 1; d < 16; d <<= 1)
#pragma unroll
            for (int r = 0; r < 4; ++r)
                mx[r] = fmaxf(mx[r], __shfl_xor(mx[r], d));
#pragma unroll
        for (int r = 0; r < 4; ++r) {
            float mnew = fmaxf(m2[r], mx[r] * C);
            alpha[r] = __builtin_amdgcn_exp2f(m2[r] - mnew);
            m2[r] = mnew;
            rs[r] = 0.f;
#pragma unroll
            for (int n = 0; n < 4; ++n) {
                float pv = __builtin_amdgcn_exp2f(__builtin_fmaf(s[n][r], C, -mnew));
                s[n][r] = pv;
                rs[r] += pv;
            }
        }
#pragma unroll
        for (int d = 1; d < 16; d <<= 1)
#pragma unroll
            for (int r = 0; r < 4; ++r)
                rs[r] += __shfl_xor(rs[r], d);
#pragma unroll
        for (int r = 0; r < 4; ++r) {
            l_run[r] = l_run[r] * alpha[r] + rs[r];
#pragma unroll
            for (int n = 0; n < 4; ++n) o[n][r] *= alpha[r];
        }

        // P: C-layout -> LDS (wave-private 16-row strip), rotated cols.
        // No barrier needed: Ps rows are wave-private; within-wave RAW is
        // ordered by lgkmcnt.
#pragma unroll
        for (int n = 0; n < 4; ++n) {
            int pc = (n * 16 + l16 + Rp) & 63;
#pragma unroll
            for (int r = 0; r < 4; ++r)
                Ps[(w * 16 + quad * 4 + r) * 72 + pc] = f2bf(s[n][r]);
        }

        // O += P @ V   (contraction over 64 keys)
#pragma unroll
        for (int kk = 0; kk < 2; ++kk) {
            bf16x8 ap = *(const bf16x8*)&Ps[(w * 16 + l16) * 72 + ((kk * 32 + quad * 8 + Rr) & 63)];
#pragma unroll
            for (int n = 0; n < 4; ++n) {
                bf16x8 bv = *(const bf16x8*)&Vt[(n * 16 + l16) * 72
                              + ((kk * 32 + quad * 8 + n * 16 + (l16 & 8)) & 63)];
                o[n] = __builtin_amdgcn_mfma_f32_16x16x32_bf16(ap, bv, o[n], 0, 0, 0);
            }
        }
    }

#pragma unroll
    for (int r = 0; r < 4; ++r) {
        float inv = 1.0f / l_run[r];
        int row = qrow0 + w * 16 + quad * 4 + r;
#pragma unroll
        for (int n = 0; n < 4; ++n) {
            int col = h * 64 + n * 16 + l16;
            o_dst[(size_t)row * ldo + col] = f2bf(o[n][r] * inv);
        }
    }
}

// ---------------------------------------------------------------------------
extern "C" void kernel_launch(void* const* d_in, const int* in_sizes, int n_in,
                              void* d_out, int out_size, void* d_ws, size_t ws_size,
                              hipStream_t stream)
{
    const float* h    = (const float*)d_in[0];
    const float* Wdkv = (const float*)d_in[1];
    const float* bdkv = (const float*)d_in[2];
    const float* Wuk  = (const float*)d_in[3];
    const float* buk  = (const float*)d_in[4];
    const float* Wuv  = (const float*)d_in[5];
    const float* buv  = (const float*)d_in[6];
    const float* Wdq  = (const float*)d_in[7];
    const float* bdq  = (const float*)d_in[8];
    const float* Wuq  = (const float*)d_in[9];
    const float* buq  = (const float*)d_in[10];
    const float* Wqr  = (const float*)d_in[11];
    const float* bqr  = (const float*)d_in[12];
    const float* Wkr  = (const float*)d_in[13];
    const float* bkr  = (const float*)d_in[14];
    const float* Wfc  = (const float*)d_in[15];
    const float* bfc  = (const float*)d_in[16];

    // Workspace layout (98,062,592 B total):
    //   out1      : 8192 x 1088 bf16  [c_kv | c_q | k_r]; attn out -> cols 0..1023
    //   out2a/hbf : 8192 x 2048 bf16  (h-bf16 during stage 1; [k_c|v_c] after)
    //   out2b     : 8192 x 2048 bf16  [q_c | q_r]
    //   w1        : 1152 x 2048 bf16  [Wdkv;Wdq;Wkr;zero-pad]
    //   w2a,w2b   : 2048 x 512 bf16   [Wuk;Wuv], [Wuq;Wqr]
    //   wfc       : 2048 x 1024 bf16
    //   bias_s1   : 1088 fp32 [bdkv|bdq|bkr];  bias_2: 4096 fp32 [buk|buv|buq|bqr]
    char* ws = (char*)d_ws;
    u16* out1   = (u16*)ws;                              // 17,825,792 B
    u16* hbf    = (u16*)(ws + 17825792);                 // 33,554,432 B (= out2a)
    u16* out2a  = hbf;
    u16* out2b  = (u16*)(ws + 51380224);                 // 33,554,432 B
    u16* w1     = (u16*)(ws + 84934656);                 //  4,718,592 B
    u16* w2a    = (u16*)(ws + 89653248);                 //  2,097,152 B
    u16* w2b    = (u16*)(ws + 91750400);                 //  2,097,152 B
    u16* wfc    = (u16*)(ws + 93847552);                 //  4,194,304 B
    float* bias_s1 = (float*)(ws + 98041856);            //      4,352 B
    float* bias_2  = (float*)(ws + 98046208);            //     16,384 B

    // --- conversion pass: h + all weights -> bf16 (8-elem chunks) ---
    Cvt9 cd;
    const float* srcs[9] = { h, Wdkv, Wdq, Wkr, Wuk, Wuv, Wuq, Wqr, Wfc };
    u16* dsts[9] = { hbf, w1, w1 + 512 * 2048, w1 + 1024 * 2048,
                     w2a, w2a + 1024 * 512, w2b, w2b + 1024 * 512, wfc };
    int cnts[9] = { 2097152, 131072, 131072, 16384, 65536, 65536, 65536, 65536, 262144 };
    int acc2 = 0;
    for (int i = 0; i < 9; ++i) { cd.src[i] = srcs[i]; cd.dst[i] = dsts[i]; acc2 += cnts[i]; cd.end[i] = acc2; }
    cvt_all<<<(acc2 + 255) / 256, 256, 0, stream>>>(cd, acc2);
    // zero-pad w1 rows 1088..1151
    hipMemsetAsync(w1 + 1088 * 2048, 0, 64 * 2048 * sizeof(u16), stream);

    // --- bias concat (fp32) ---
    Cpy7 bc;
    const float* bs[7] = { bdkv, bdq, bkr, buk, buv, buq, bqr };
    float* bd[7] = { bias_s1, bias_s1 + 512, bias_s1 + 1024,
                     bias_2, bias_2 + 1024, bias_2 + 2048, bias_2 + 3072 };
    int bn[7] = { 512, 512, 64, 1024, 1024, 1024, 1024 };
    int bacc = 0;
    for (int i = 0; i < 7; ++i) { bc.src[i] = bs[i]; bc.dst[i] = bd[i]; bacc += bn[i]; bc.end[i] = bacc; }
    copy_f32<<<(bacc + 255) / 256, 256, 0, stream>>>(bc, bacc);

    // --- stage 1: [c_kv|c_q|k_r] = hbf @ w1^T, N=1088, K=2048 ---
    gemm_v5<false><<<dim3(64, 9), 256, 0, stream>>>(
        hbf, w1, out1, bias_s1,
        hbf, w1, out1, bias_s1, 9, 2048, 2048, 1088, 1088, 2048);
    rope_inplace<<<1024, 256, 0, stream>>>(out1, 1088, 1024, 32, 8192 * 32);   // k_r

    // --- stage 2 (fused 2a+2b): K=512, N=2048 each half ---
    gemm_v5<false><<<dim3(64, 32), 256, 0, stream>>>(
        out1,       w2a, out2a, bias_2,
        out1 + 512, w2b, out2b, bias_2 + 2048, 16, 1088, 512, 2048, 2048, 512);
    rope_inplace<<<16384, 256, 0, stream>>>(out2b, 2048, 1024, 512, 8192 * 512);  // q_r

    // --- attention: 1-D grid, temporal XCD swizzle inside the kernel ---
    attn_kernel<<<2048, 256, 0, stream>>>(out2b, out2a, out1, out1, 1088);

    // --- final projection: d_out = attn @ wfc^T, fp32 out ---
    gemm_v5<true><<<dim3(64, 16), 256, 0, stream>>>(
        out1, wfc, d_out, bfc,
        out1, wfc, d_out, bfc, 16, 1088, 1024, 2048, 2048, 1024);
}

// Round 7
// 424.220 us; speedup vs baseline: 1.0252x; 1.0252x over previous
//
#include <hip/hip_runtime.h>
#include <hip/hip_bf16.h>

typedef __bf16 bf16x8 __attribute__((ext_vector_type(8)));
typedef float f32x4 __attribute__((ext_vector_type(4)));
using u16 = unsigned short;
using u32 = unsigned int;

__device__ __forceinline__ float bf2f(u16 v) {
    unsigned int u = (unsigned int)v << 16;
    float f; __builtin_memcpy(&f, &u, 4); return f;
}
__device__ __forceinline__ u16 f2bf(float f) {
    unsigned int u; __builtin_memcpy(&u, &f, 4);
    u += 0x7FFFu + ((u >> 16) & 1u);   // RNE (finite data only)
    return (u16)(u >> 16);
}

// ---------------------------------------------------------------------------
// Bulk fp32 -> bf16 conversion, 9 segments, 8 elems/thread.
// ---------------------------------------------------------------------------
struct Cvt9 {
    const float* src[9];
    u16* dst[9];
    int end[9];      // cumulative chunk ends (chunks of 8 elems)
};
__global__ __launch_bounds__(256) void cvt_all(Cvt9 d, int total)
{
    int c = blockIdx.x * 256 + threadIdx.x;
    if (c >= total) return;
    int seg = 0;
    while (c >= d.end[seg]) ++seg;
    int local = c - (seg ? d.end[seg - 1] : 0);
    const float* s = d.src[seg] + (size_t)local * 8;
    float4 f0 = *(const float4*)s;
    float4 f1 = *(const float4*)(s + 4);
    u16 tmp[8] = { f2bf(f0.x), f2bf(f0.y), f2bf(f0.z), f2bf(f0.w),
                   f2bf(f1.x), f2bf(f1.y), f2bf(f1.z), f2bf(f1.w) };
    *(uint4*)(d.dst[seg] + (size_t)local * 8) = *(const uint4*)tmp;
}

// ---------------------------------------------------------------------------
// Bias concatenation (fp32 copy, 7 segments).
// ---------------------------------------------------------------------------
struct Cpy7 {
    const float* src[7];
    float* dst[7];
    int end[7];
};
__global__ __launch_bounds__(256) void copy_f32(Cpy7 d, int total)
{
    int c = blockIdx.x * 256 + threadIdx.x;
    if (c >= total) return;
    int seg = 0;
    while (c >= d.end[seg]) ++seg;
    int local = c - (seg ? d.end[seg - 1] : 0);
    d.dst[seg][local] = d.src[seg][local];
}

// ---------------------------------------------------------------------------
// Pure-bf16 C = A @ B^T + bias GEMM, two independent "halves" selected by
// blockIdx.y < ysplit.  v6 = v5 WITHOUT sched_barrier(0) order-pinning
// (m141: pinning defeats the compiler scheduler).  3-buffer LDS pipeline
// (BK=32, 48 KB), counted vmcnt, raw s_barrier; swapped-operand MFMA for a
// vectorized epilogue (lane holds 4 consecutive C columns of one row).
// ---------------------------------------------------------------------------
template<bool CF>
__global__ __launch_bounds__(256) void gemm_v6(
    const u16* __restrict__ A0, const u16* __restrict__ B0, void* __restrict__ C0, const float* __restrict__ e0,
    const u16* __restrict__ A1, const u16* __restrict__ B1, void* __restrict__ C1, const float* __restrict__ e1,
    int ysplit, int lda, int ldb, int ldc, int N, int K)
{
    __shared__ __align__(16) u16 As[3][128 * 32];
    __shared__ __align__(16) u16 Bs[3][128 * 32];

    const int t = threadIdx.x;
    const int lane = t & 63;
    const int w = t >> 6;
    const int wm = w >> 1, wn = w & 1;
    const int l16 = lane & 15, quad = lane >> 4;
    const int m0 = blockIdx.x * 128;

    const u16* A; const u16* B; void* Cv; const float* bias; int yl;
    if ((int)blockIdx.y < ysplit) { A = A0; B = B0; Cv = C0; bias = e0; yl = blockIdx.y; }
    else                          { A = A1; B = B1; Cv = C1; bias = e1; yl = blockIdx.y - ysplit; }
    const int n0 = yl * 128;

    const int sub  = lane >> 2;                 // 0..15: row within 16-row chunk
    const int slot = lane & 3;                  // 16B slot within 64B row
    const int agc  = slot ^ ((sub >> 1) & 3);   // swizzled global chunk
    const int sfr  = (l16 >> 1) & 3;            // fragment-read unswizzle

    f32x4 acc[4][4];
#pragma unroll
    for (int i = 0; i < 4; ++i)
#pragma unroll
        for (int j = 0; j < 4; ++j) acc[i][j] = (f32x4){0.f, 0.f, 0.f, 0.f};

    auto STAGE = [&](int buf, int k0) {
#pragma unroll
        for (int c = 0; c < 2; ++c) {
            const int rr = w * 32 + c * 16;
            const u16* ga = A + (size_t)(m0 + rr + sub) * lda + k0 + agc * 8;
            __builtin_amdgcn_global_load_lds(
                (const __attribute__((address_space(1))) u32*)ga,
                (__attribute__((address_space(3))) u32*)&As[buf][rr * 32], 16, 0, 0);
            const u16* gb = B + (size_t)(n0 + rr + sub) * ldb + k0 + agc * 8;
            __builtin_amdgcn_global_load_lds(
                (const __attribute__((address_space(1))) u32*)gb,
                (__attribute__((address_space(3))) u32*)&Bs[buf][rr * 32], 16, 0, 0);
        }
    };

    const int nt = K >> 5;
    STAGE(0, 0);
    STAGE(1, 32);
    int cur = 0;
    for (int tt = 0; tt < nt; ++tt) {
        int pre = cur + 2; if (pre >= 3) pre -= 3;
        if (tt + 2 < nt) {
            STAGE(pre, (tt + 2) << 5);
            asm volatile("s_waitcnt vmcnt(8)");   // tile tt's 4 loads landed
        } else if (tt + 1 < nt) {
            asm volatile("s_waitcnt vmcnt(4)");
        } else {
            asm volatile("s_waitcnt vmcnt(0)");
        }
        __builtin_amdgcn_s_barrier();             // everyone's tile-tt loads landed

        const u16* Ab = As[cur];
        const u16* Bb = Bs[cur];
        bf16x8 af[4], bfr[4];
#pragma unroll
        for (int i = 0; i < 4; ++i)
            af[i] = *(const bf16x8*)&Ab[(wm * 64 + i * 16 + l16) * 32 + (quad ^ sfr) * 8];
#pragma unroll
        for (int j = 0; j < 4; ++j)
            bfr[j] = *(const bf16x8*)&Bs[cur][(wn * 64 + j * 16 + l16) * 32 + (quad ^ sfr) * 8];
#pragma unroll
        for (int i = 0; i < 4; ++i)
#pragma unroll
            for (int j = 0; j < 4; ++j)
                acc[i][j] = __builtin_amdgcn_mfma_f32_16x16x32_bf16(bfr[j], af[i], acc[i][j], 0, 0, 0);

        __builtin_amdgcn_s_barrier();             // done reading cur -> restageable
        cur += 1; if (cur >= 3) cur -= 3;
        (void)Bb;
    }

    // Swapped-operand C layout: acc[i][j][r] = C[m0+wm*64+i*16+l16]
    //                                           [n0+wn*64+j*16+quad*4+r]
#pragma unroll
    for (int i = 0; i < 4; ++i) {
        const int row = m0 + wm * 64 + i * 16 + l16;
#pragma unroll
        for (int j = 0; j < 4; ++j) {
            const int colb = n0 + wn * 64 + j * 16 + quad * 4;
            if (colb >= N) continue;
            float4 bv = *(const float4*)&bias[colb];
            float v0 = acc[i][j][0] + bv.x;
            float v1 = acc[i][j][1] + bv.y;
            float v2 = acc[i][j][2] + bv.z;
            float v3 = acc[i][j][3] + bv.w;
            if (CF) {
                float4 out = { v0, v1, v2, v3 };
                *(float4*)((float*)Cv + (size_t)row * ldc + colb) = out;
            } else {
                u16 p[4] = { f2bf(v0), f2bf(v1), f2bf(v2), f2bf(v3) };
                *(uint2*)((u16*)Cv + (size_t)row * ldc + colb) = *(const uint2*)p;
            }
        }
    }
}

// ---------------------------------------------------------------------------
// RoPE in place on bf16 ws buffers (source quirk: cos_pos = sin, sin_pos =
// cos):  out[2i] = x[2i]*sin - x[2i+1]*cos ; out[2i+1] = x[2i+1]*sin +
// x[2i]*cos ;  ang = (row % 512) * 10000^(-i/32).
// ---------------------------------------------------------------------------
__global__ void rope_inplace(u16* __restrict__ buf, int ld, int col0, int ppr, int total)
{
    int idx = blockIdx.x * 256 + threadIdx.x;
    if (idx >= total) return;
    int row = idx / ppr;
    int pi  = idx - row * ppr;
    int grp = pi >> 5;
    int i   = pi & 31;
    int pos = row & 511;
    float theta = __expf(-(float)i * 0.2878231366242558f);  // ln(10000)/32
    float ang = (float)pos * theta;
    float s = sinf(ang), c = cosf(ang);
    size_t base = (size_t)row * ld + col0 + grp * 64 + 2 * i;
    float x0 = bf2f(buf[base]);
    float x1 = bf2f(buf[base + 1]);
    buf[base]     = f2bf(x0 * s - x1 * c);
    buf[base + 1] = f2bf(x1 * s + x0 * c);
}

// ---------------------------------------------------------------------------
// Flash attention.  v7: SWAPPED QK^T — s[n] = mfma(K_frag, Q_frag, s[n]) so
// the C-layout puts q = l16 (one q-row per lane), keys = 16n + 4*quad + r.
// Softmax: 15 in-lane fmax/adds + 2 shfl_xor (quad halves) per reduce
// (was 32 shfl/kt); m/l/alpha are scalars; alpha redistributed to the
// PV o-layout (rows quad*4+r) with 4 __shfl from lanes quad*4+r (<16).
// P-store: key pairs are lane-adjacent -> 8 u32 stores, 8-col-granule XOR
// swizzle (gb ^= row&7) applied on write AND b128 read.
// PV, Vt staging, temporal XCD swizzle, raw-barrier async staging unchanged.
// ---------------------------------------------------------------------------
__global__ __launch_bounds__(256) void attn_kernel(
    const u16* __restrict__ q_src,   // 8192 x 2048 : [q_c | q_r(roped)]
    const u16* __restrict__ kv_src,  // 8192 x 2048 : [k_c | v_c]
    const u16* __restrict__ kr_src,  // 8192 x 1088 : k_r at col 1024 (roped)
    u16* __restrict__ o_dst, int ldo)
{
    __shared__ __align__(16) u16 Ks[64 * 136];
    __shared__ __align__(16) u16 Vt[64 * 72];   // [vd][key] rotated
    __shared__ __align__(16) u16 Ps[64 * 72];   // [q][key] granule-XOR'd

    const int t = threadIdx.x;
    const int lane = t & 63;
    const int w = t >> 6;
    const int l16 = lane & 15, quad = lane >> 4;
    const int a7 = l16 & 7;

    const int id   = blockIdx.x;
    const int xcd  = id & 7;
    const int qt   = (id >> 3) & 7;
    const int panel = xcd + ((id >> 6) << 3);   // 0..255
    const int h = panel & 15;
    const int b = panel >> 4;
    const int qrow0 = b * 512 + qt * 64;
    const int krow_base = b * 512;

    // Q fragments straight to registers: wave w owns q rows w*16..w*16+15.
    bf16x8 aq[4];
    {
        const u16* qrow = q_src + (size_t)(qrow0 + w * 16 + l16) * 2048;
#pragma unroll
        for (int ks = 0; ks < 4; ++ks) {
            int col = ks * 32 + quad * 8;
            const u16* src = (col < 64) ? qrow + h * 64 + col
                                        : qrow + 1024 + h * 64 + (col - 64);
            aq[ks] = *(const bf16x8*)src;
        }
    }

    // --- staging geometry (kt-independent) ---
    const int colK = (t & 15) * 8;            // K column chunk (u16)
    const int r0k  = t >> 4;                  // K row 0..15 (+16p)
    const u16* kbase; int kstr;
    if (colK < 64) { kbase = kv_src + h * 64 + colK;        kstr = 2048; }
    else           { kbase = kr_src + 1024 + (colK - 64);   kstr = 1088; }
    u16* kw = &Ks[r0k * 136 + colK];

    const int v00 = (t & 7) * 8;              // vd chunk
    const int r0v = t >> 3;                   // key row 0..31 (+32p)
    const u16* vbase = kv_src + 1024 + h * 64 + v00;
    const int rotA = (r0v + v00) & 63;
    const int rotB = (r0v + 32 + v00) & 63;
    u16* vwA = &Vt[v00 * 72 + rotA];
    u16* vwB = &Vt[v00 * 72 + rotB];

    auto LOADT = [&](int krow0, uint4& K0, uint4& K1, uint4& K2, uint4& K3,
                     uint4& V0, uint4& V1) {
        K0 = *(const uint4*)(kbase + (size_t)(krow0 + r0k     ) * kstr);
        K1 = *(const uint4*)(kbase + (size_t)(krow0 + r0k + 16) * kstr);
        K2 = *(const uint4*)(kbase + (size_t)(krow0 + r0k + 32) * kstr);
        K3 = *(const uint4*)(kbase + (size_t)(krow0 + r0k + 48) * kstr);
        V0 = *(const uint4*)(vbase + (size_t)(krow0 + r0v     ) * 2048);
        V1 = *(const uint4*)(vbase + (size_t)(krow0 + r0v + 32) * 2048);
    };
    auto WRITET = [&](const uint4& K0, const uint4& K1, const uint4& K2, const uint4& K3,
                      const uint4& V0, const uint4& V1) {
        *(uint4*)(kw)            = K0;
        *(uint4*)(kw + 16 * 136) = K1;
        *(uint4*)(kw + 32 * 136) = K2;
        *(uint4*)(kw + 48 * 136) = K3;
        u16 ta[8], tb[8];
        __builtin_memcpy(ta, &V0, 16);
        __builtin_memcpy(tb, &V1, 16);
#pragma unroll
        for (int j2 = 0; j2 < 8; ++j2) { vwA[j2 * 72] = ta[j2]; vwB[j2 * 72] = tb[j2]; }
    };

    float m2 = -1e30f, l_run = 0.f;           // per-lane: q-row l16 (log2 dom.)
    f32x4 o[4];
#pragma unroll
    for (int n = 0; n < 4; ++n) o[n] = (f32x4){0.f, 0.f, 0.f, 0.f};

    const float C = 0.10411756f;              // log2(e)/sqrt(192)

    uint4 kA0, kA1, kA2, kA3, vA0, vA1;
    uint4 kB0, kB1, kB2, kB3, vB0, vB1;
    LOADT(krow_base, kA0, kA1, kA2, kA3, vA0, vA1);   // kt = 0

    for (int kt = 0; kt < 8; ++kt) {
        // (A) all waves done reading Ks/Vt of previous tile
        __builtin_amdgcn_s_barrier();
        if ((kt & 1) == 0) {
            WRITET(kA0, kA1, kA2, kA3, vA0, vA1);
            if (kt < 7) LOADT(krow_base + (kt + 1) * 64, kB0, kB1, kB2, kB3, vB0, vB1);
        } else {
            WRITET(kB0, kB1, kB2, kB3, vB0, vB1);
            if (kt < 7) LOADT(krow_base + (kt + 1) * 64, kA0, kA1, kA2, kA3, vA0, vA1);
        }
        asm volatile("s_waitcnt lgkmcnt(0)");     // my ds_writes visible
        __builtin_amdgcn_sched_barrier(0);
        // (B) everyone's ds_writes visible; vmcnt NOT drained -> prefetch flies
        __builtin_amdgcn_s_barrier();

        // S strip, SWAPPED: s[n] = K_n Q^T -> lane holds S[key=16n+4q+r][q=l16]
        f32x4 s[4];
#pragma unroll
        for (int n = 0; n < 4; ++n) s[n] = (f32x4){0.f, 0.f, 0.f, 0.f};
#pragma unroll
        for (int ks = 0; ks < 4; ++ks) {
#pragma unroll
            for (int n = 0; n < 4; ++n) {
                bf16x8 bk = *(const bf16x8*)&Ks[(n * 16 + l16) * 136 + ks * 32 + quad * 8];
                s[n] = __builtin_amdgcn_mfma_f32_16x16x32_bf16(bk, aq[ks], s[n], 0, 0, 0);
            }
        }

        // online softmax (log2 domain), row = q = l16 per lane
        float mx = fmaxf(fmaxf(s[0][0], s[0][1]), fmaxf(s[0][2], s[0][3]));
#pragma unroll
        for (int n = 1; n < 4; ++n)
            mx = fmaxf(mx, fmaxf(fmaxf(s[n][0], s[n][1]), fmaxf(s[n][2], s[n][3])));
        mx = fmaxf(mx, __shfl_xor(mx, 16));
        mx = fmaxf(mx, __shfl_xor(mx, 32));

        float mnew = fmaxf(m2, mx * C);
        float alpha = __builtin_amdgcn_exp2f(m2 - mnew);
        m2 = mnew;
        float rs = 0.f;
#pragma unroll
        for (int n = 0; n < 4; ++n)
#pragma unroll
            for (int r = 0; r < 4; ++r) {
                float pv = __builtin_amdgcn_exp2f(__builtin_fmaf(s[n][r], C, -mnew));
                s[n][r] = pv;
                rs += pv;
            }
        rs += __shfl_xor(rs, 16);
        rs += __shfl_xor(rs, 32);
        l_run = l_run * alpha + rs;

        // redistribute alpha to o-layout rows (q = quad*4+r lives at lane q<16)
        float aO[4];
#pragma unroll
        for (int r = 0; r < 4; ++r) aO[r] = __shfl(alpha, quad * 4 + r);
#pragma unroll
        for (int n = 0; n < 4; ++n)
#pragma unroll
            for (int r = 0; r < 4; ++r) o[n][r] *= aO[r];

        // P -> LDS: row q=w*16+l16 (wave-private), keys 16n+4*quad+{0..3}.
        // 8-col granule XOR swizzle: gb' = gb ^ (row&7).  8 u32 stores.
        {
            u16* prow = &Ps[(w * 16 + l16) * 72];
#pragma unroll
            for (int n = 0; n < 4; ++n) {
                int cb = n * 16 + quad * 4;
                int pc = (((cb >> 3) ^ a7) << 3) + (cb & 7);
                u32 p0 = (u32)f2bf(s[n][0]) | ((u32)f2bf(s[n][1]) << 16);
                u32 p1 = (u32)f2bf(s[n][2]) | ((u32)f2bf(s[n][3]) << 16);
                *(u32*)&prow[pc]     = p0;
                *(u32*)&prow[pc + 2] = p1;
            }
        }

        // O += P @ V   (contraction over 64 keys); Ps read undoes granule XOR
#pragma unroll
        for (int kk = 0; kk < 2; ++kk) {
            int gb = 4 * kk + quad;
            bf16x8 ap = *(const bf16x8*)&Ps[(w * 16 + l16) * 72 + ((gb ^ a7) << 3)];
#pragma unroll
            for (int n = 0; n < 4; ++n) {
                bf16x8 bv = *(const bf16x8*)&Vt[(n * 16 + l16) * 72
                              + ((kk * 32 + quad * 8 + n * 16 + (l16 & 8)) & 63)];
                o[n] = __builtin_amdgcn_mfma_f32_16x16x32_bf16(ap, bv, o[n], 0, 0, 0);
            }
        }
    }

    // epilogue: inv(l_run) lives at lane q (<16); o rows are quad*4+r
    float inv = 1.0f / l_run;
#pragma unroll
    for (int r = 0; r < 4; ++r) {
        float invO = __shfl(inv, quad * 4 + r);
        int row = qrow0 + w * 16 + quad * 4 + r;
#pragma unroll
        for (int n = 0; n < 4; ++n) {
            int col = h * 64 + n * 16 + l16;
            o_dst[(size_t)row * ldo + col] = f2bf(o[n][r] * invO);
        }
    }
}

// ---------------------------------------------------------------------------
extern "C" void kernel_launch(void* const* d_in, const int* in_sizes, int n_in,
                              void* d_out, int out_size, void* d_ws, size_t ws_size,
                              hipStream_t stream)
{
    const float* h    = (const float*)d_in[0];
    const float* Wdkv = (const float*)d_in[1];
    const float* bdkv = (const float*)d_in[2];
    const float* Wuk  = (const float*)d_in[3];
    const float* buk  = (const float*)d_in[4];
    const float* Wuv  = (const float*)d_in[5];
    const float* buv  = (const float*)d_in[6];
    const float* Wdq  = (const float*)d_in[7];
    const float* bdq  = (const float*)d_in[8];
    const float* Wuq  = (const float*)d_in[9];
    const float* buq  = (const float*)d_in[10];
    const float* Wqr  = (const float*)d_in[11];
    const float* bqr  = (const float*)d_in[12];
    const float* Wkr  = (const float*)d_in[13];
    const float* bkr  = (const float*)d_in[14];
    const float* Wfc  = (const float*)d_in[15];
    const float* bfc  = (const float*)d_in[16];

    // Workspace layout (98,062,592 B total):
    //   out1      : 8192 x 1088 bf16  [c_kv | c_q | k_r]; attn out -> cols 0..1023
    //   out2a/hbf : 8192 x 2048 bf16  (h-bf16 during stage 1; [k_c|v_c] after)
    //   out2b     : 8192 x 2048 bf16  [q_c | q_r]
    //   w1        : 1152 x 2048 bf16  [Wdkv;Wdq;Wkr;zero-pad]
    //   w2a,w2b   : 2048 x 512 bf16   [Wuk;Wuv], [Wuq;Wqr]
    //   wfc       : 2048 x 1024 bf16
    //   bias_s1   : 1088 fp32 [bdkv|bdq|bkr];  bias_2: 4096 fp32 [buk|buv|buq|bqr]
    char* ws = (char*)d_ws;
    u16* out1   = (u16*)ws;                              // 17,825,792 B
    u16* hbf    = (u16*)(ws + 17825792);                 // 33,554,432 B (= out2a)
    u16* out2a  = hbf;
    u16* out2b  = (u16*)(ws + 51380224);                 // 33,554,432 B
    u16* w1     = (u16*)(ws + 84934656);                 //  4,718,592 B
    u16* w2a    = (u16*)(ws + 89653248);                 //  2,097,152 B
    u16* w2b    = (u16*)(ws + 91750400);                 //  2,097,152 B
    u16* wfc    = (u16*)(ws + 93847552);                 //  4,194,304 B
    float* bias_s1 = (float*)(ws + 98041856);            //      4,352 B
    float* bias_2  = (float*)(ws + 98046208);            //     16,384 B

    // --- conversion pass: h + all weights -> bf16 (8-elem chunks) ---
    Cvt9 cd;
    const float* srcs[9] = { h, Wdkv, Wdq, Wkr, Wuk, Wuv, Wuq, Wqr, Wfc };
    u16* dsts[9] = { hbf, w1, w1 + 512 * 2048, w1 + 1024 * 2048,
                     w2a, w2a + 1024 * 512, w2b, w2b + 1024 * 512, wfc };
    int cnts[9] = { 2097152, 131072, 131072, 16384, 65536, 65536, 65536, 65536, 262144 };
    int acc2 = 0;
    for (int i = 0; i < 9; ++i) { cd.src[i] = srcs[i]; cd.dst[i] = dsts[i]; acc2 += cnts[i]; cd.end[i] = acc2; }
    cvt_all<<<(acc2 + 255) / 256, 256, 0, stream>>>(cd, acc2);
    // zero-pad w1 rows 1088..1151
    hipMemsetAsync(w1 + 1088 * 2048, 0, 64 * 2048 * sizeof(u16), stream);

    // --- bias concat (fp32) ---
    Cpy7 bc;
    const float* bs[7] = { bdkv, bdq, bkr, buk, buv, buq, bqr };
    float* bd[7] = { bias_s1, bias_s1 + 512, bias_s1 + 1024,
                     bias_2, bias_2 + 1024, bias_2 + 2048, bias_2 + 3072 };
    int bn[7] = { 512, 512, 64, 1024, 1024, 1024, 1024 };
    int bacc = 0;
    for (int i = 0; i < 7; ++i) { bc.src[i] = bs[i]; bc.dst[i] = bd[i]; bacc += bn[i]; bc.end[i] = bacc; }
    copy_f32<<<(bacc + 255) / 256, 256, 0, stream>>>(bc, bacc);

    // --- stage 1: [c_kv|c_q|k_r] = hbf @ w1^T, N=1088, K=2048 ---
    gemm_v6<false><<<dim3(64, 9), 256, 0, stream>>>(
        hbf, w1, out1, bias_s1,
        hbf, w1, out1, bias_s1, 9, 2048, 2048, 1088, 1088, 2048);
    rope_inplace<<<1024, 256, 0, stream>>>(out1, 1088, 1024, 32, 8192 * 32);   // k_r

    // --- stage 2 (fused 2a+2b): K=512, N=2048 each half ---
    gemm_v6<false><<<dim3(64, 32), 256, 0, stream>>>(
        out1,       w2a, out2a, bias_2,
        out1 + 512, w2b, out2b, bias_2 + 2048, 16, 1088, 512, 2048, 2048, 512);
    rope_inplace<<<16384, 256, 0, stream>>>(out2b, 2048, 1024, 512, 8192 * 512);  // q_r

    // --- attention: 1-D grid, temporal XCD swizzle inside the kernel ---
    attn_kernel<<<2048, 256, 0, stream>>>(out2b, out2a, out1, out1, 1088);

    // --- final projection: d_out = attn @ wfc^T, fp32 out ---
    gemm_v6<true><<<dim3(64, 16), 256, 0, stream>>>(
        out1, wfc, d_out, bfc,
        out1, wfc, d_out, bfc, 16, 1088, 1024, 2048, 2048, 1024);
}

// Round 8
// 414.310 us; speedup vs baseline: 1.0497x; 1.0239x over previous
//
#include <hip/hip_runtime.h>
#include <hip/hip_bf16.h>

typedef __bf16 bf16x8 __attribute__((ext_vector_type(8)));
typedef float f32x4 __attribute__((ext_vector_type(4)));
using u16 = unsigned short;
using u32 = unsigned int;

__device__ __forceinline__ float bf2f(u16 v) {
    unsigned int u = (unsigned int)v << 16;
    float f; __builtin_memcpy(&f, &u, 4); return f;
}
__device__ __forceinline__ u16 f2bf(float f) {
    unsigned int u; __builtin_memcpy(&u, &f, 4);
    u += 0x7FFFu + ((u >> 16) & 1u);   // RNE (finite data only)
    return (u16)(u >> 16);
}

// ---------------------------------------------------------------------------
// Bulk fp32 -> bf16 conversion, 9 segments, 8 elems/thread.
// ---------------------------------------------------------------------------
struct Cvt9 {
    const float* src[9];
    u16* dst[9];
    int end[9];      // cumulative chunk ends (chunks of 8 elems)
};
__global__ __launch_bounds__(256) void cvt_all(Cvt9 d, int total)
{
    int c = blockIdx.x * 256 + threadIdx.x;
    if (c >= total) return;
    int seg = 0;
    while (c >= d.end[seg]) ++seg;
    int local = c - (seg ? d.end[seg - 1] : 0);
    const float* s = d.src[seg] + (size_t)local * 8;
    float4 f0 = *(const float4*)s;
    float4 f1 = *(const float4*)(s + 4);
    u16 tmp[8] = { f2bf(f0.x), f2bf(f0.y), f2bf(f0.z), f2bf(f0.w),
                   f2bf(f1.x), f2bf(f1.y), f2bf(f1.z), f2bf(f1.w) };
    *(uint4*)(d.dst[seg] + (size_t)local * 8) = *(const uint4*)tmp;
}

// ---------------------------------------------------------------------------
// Bias concatenation (fp32 copy, 7 segments).
// ---------------------------------------------------------------------------
struct Cpy7 {
    const float* src[7];
    float* dst[7];
    int end[7];
};
__global__ __launch_bounds__(256) void copy_f32(Cpy7 d, int total)
{
    int c = blockIdx.x * 256 + threadIdx.x;
    if (c >= total) return;
    int seg = 0;
    while (c >= d.end[seg]) ++seg;
    int local = c - (seg ? d.end[seg - 1] : 0);
    d.dst[seg][local] = d.src[seg][local];
}

// ---------------------------------------------------------------------------
// Pure-bf16 C = A @ B^T + bias GEMM, two independent "halves" selected by
// blockIdx.y < ysplit.  3-buffer LDS pipeline (BK=32, 48 KB), counted vmcnt,
// raw s_barrier; swapped-operand MFMA for a vectorized epilogue (lane holds
// 4 consecutive C columns of one row).
// ---------------------------------------------------------------------------
template<bool CF>
__global__ __launch_bounds__(256) void gemm_v6(
    const u16* __restrict__ A0, const u16* __restrict__ B0, void* __restrict__ C0, const float* __restrict__ e0,
    const u16* __restrict__ A1, const u16* __restrict__ B1, void* __restrict__ C1, const float* __restrict__ e1,
    int ysplit, int lda, int ldb, int ldc, int N, int K)
{
    __shared__ __align__(16) u16 As[3][128 * 32];
    __shared__ __align__(16) u16 Bs[3][128 * 32];

    const int t = threadIdx.x;
    const int lane = t & 63;
    const int w = t >> 6;
    const int wm = w >> 1, wn = w & 1;
    const int l16 = lane & 15, quad = lane >> 4;
    const int m0 = blockIdx.x * 128;

    const u16* A; const u16* B; void* Cv; const float* bias; int yl;
    if ((int)blockIdx.y < ysplit) { A = A0; B = B0; Cv = C0; bias = e0; yl = blockIdx.y; }
    else                          { A = A1; B = B1; Cv = C1; bias = e1; yl = blockIdx.y - ysplit; }
    const int n0 = yl * 128;

    const int sub  = lane >> 2;                 // 0..15: row within 16-row chunk
    const int slot = lane & 3;                  // 16B slot within 64B row
    const int agc  = slot ^ ((sub >> 1) & 3);   // swizzled global chunk
    const int sfr  = (l16 >> 1) & 3;            // fragment-read unswizzle

    f32x4 acc[4][4];
#pragma unroll
    for (int i = 0; i < 4; ++i)
#pragma unroll
        for (int j = 0; j < 4; ++j) acc[i][j] = (f32x4){0.f, 0.f, 0.f, 0.f};

    auto STAGE = [&](int buf, int k0) {
#pragma unroll
        for (int c = 0; c < 2; ++c) {
            const int rr = w * 32 + c * 16;
            const u16* ga = A + (size_t)(m0 + rr + sub) * lda + k0 + agc * 8;
            __builtin_amdgcn_global_load_lds(
                (const __attribute__((address_space(1))) u32*)ga,
                (__attribute__((address_space(3))) u32*)&As[buf][rr * 32], 16, 0, 0);
            const u16* gb = B + (size_t)(n0 + rr + sub) * ldb + k0 + agc * 8;
            __builtin_amdgcn_global_load_lds(
                (const __attribute__((address_space(1))) u32*)gb,
                (__attribute__((address_space(3))) u32*)&Bs[buf][rr * 32], 16, 0, 0);
        }
    };

    const int nt = K >> 5;
    STAGE(0, 0);
    STAGE(1, 32);
    int cur = 0;
    for (int tt = 0; tt < nt; ++tt) {
        int pre = cur + 2; if (pre >= 3) pre -= 3;
        if (tt + 2 < nt) {
            STAGE(pre, (tt + 2) << 5);
            asm volatile("s_waitcnt vmcnt(8)");   // tile tt's 4 loads landed
        } else if (tt + 1 < nt) {
            asm volatile("s_waitcnt vmcnt(4)");
        } else {
            asm volatile("s_waitcnt vmcnt(0)");
        }
        __builtin_amdgcn_s_barrier();             // everyone's tile-tt loads landed

        const u16* Ab = As[cur];
        bf16x8 af[4], bfr[4];
#pragma unroll
        for (int i = 0; i < 4; ++i)
            af[i] = *(const bf16x8*)&Ab[(wm * 64 + i * 16 + l16) * 32 + (quad ^ sfr) * 8];
#pragma unroll
        for (int j = 0; j < 4; ++j)
            bfr[j] = *(const bf16x8*)&Bs[cur][(wn * 64 + j * 16 + l16) * 32 + (quad ^ sfr) * 8];
#pragma unroll
        for (int i = 0; i < 4; ++i)
#pragma unroll
            for (int j = 0; j < 4; ++j)
                acc[i][j] = __builtin_amdgcn_mfma_f32_16x16x32_bf16(bfr[j], af[i], acc[i][j], 0, 0, 0);

        __builtin_amdgcn_s_barrier();             // done reading cur -> restageable
        cur += 1; if (cur >= 3) cur -= 3;
    }

    // Swapped-operand C layout: acc[i][j][r] = C[m0+wm*64+i*16+l16]
    //                                           [n0+wn*64+j*16+quad*4+r]
#pragma unroll
    for (int i = 0; i < 4; ++i) {
        const int row = m0 + wm * 64 + i * 16 + l16;
#pragma unroll
        for (int j = 0; j < 4; ++j) {
            const int colb = n0 + wn * 64 + j * 16 + quad * 4;
            if (colb >= N) continue;
            float4 bv = *(const float4*)&bias[colb];
            float v0 = acc[i][j][0] + bv.x;
            float v1 = acc[i][j][1] + bv.y;
            float v2 = acc[i][j][2] + bv.z;
            float v3 = acc[i][j][3] + bv.w;
            if (CF) {
                float4 out = { v0, v1, v2, v3 };
                *(float4*)((float*)Cv + (size_t)row * ldc + colb) = out;
            } else {
                u16 p[4] = { f2bf(v0), f2bf(v1), f2bf(v2), f2bf(v3) };
                *(uint2*)((u16*)Cv + (size_t)row * ldc + colb) = *(const uint2*)p;
            }
        }
    }
}

// ---------------------------------------------------------------------------
// RoPE in place on bf16 ws buffers (source quirk: cos_pos = sin, sin_pos =
// cos):  out[2i] = x[2i]*sin - x[2i+1]*cos ; out[2i+1] = x[2i+1]*sin +
// x[2i]*cos ;  ang = (row % 512) * 10000^(-i/32).
// ---------------------------------------------------------------------------
__global__ void rope_inplace(u16* __restrict__ buf, int ld, int col0, int ppr, int total)
{
    int idx = blockIdx.x * 256 + threadIdx.x;
    if (idx >= total) return;
    int row = idx / ppr;
    int pi  = idx - row * ppr;
    int grp = pi >> 5;
    int i   = pi & 31;
    int pos = row & 511;
    float theta = __expf(-(float)i * 0.2878231366242558f);  // ln(10000)/32
    float ang = (float)pos * theta;
    float s = sinf(ang), c = cosf(ang);
    size_t base = (size_t)row * ld + col0 + grp * 64 + 2 * i;
    float x0 = bf2f(buf[base]);
    float x1 = bf2f(buf[base + 1]);
    buf[base]     = f2bf(x0 * s - x1 * c);
    buf[base + 1] = f2bf(x1 * s + x0 * c);
}

// ---------------------------------------------------------------------------
// Flash attention.  v8 = v7 with the Ps swizzle fixed: ROTATION granule
// permutation p = (g + row&7) & 7 on 8-u16 granules (XOR version had
// degenerate bank-groups: (a7 + (g^a7)) mod 8 collapses to 2 values for
// odd g -> 4x min conflicts; rotation gives (2*a7+g) mod 8, uniform 8
// lanes/group = b128 minimum).  P-store is now one uint2 (b64) per n:
// banks 4v+2ql+{0,1}, 4 dwords/bank = b64 minimum (conflict-free).
// Everything else unchanged from v7 (swapped QK^T, scalar softmax with 2
// shfl_xor, temporal XCD swizzle, raw-barrier async staging).
// ---------------------------------------------------------------------------
__global__ __launch_bounds__(256) void attn_kernel(
    const u16* __restrict__ q_src,   // 8192 x 2048 : [q_c | q_r(roped)]
    const u16* __restrict__ kv_src,  // 8192 x 2048 : [k_c | v_c]
    const u16* __restrict__ kr_src,  // 8192 x 1088 : k_r at col 1024 (roped)
    u16* __restrict__ o_dst, int ldo)
{
    __shared__ __align__(16) u16 Ks[64 * 136];
    __shared__ __align__(16) u16 Vt[64 * 72];   // [vd][key] rotated
    __shared__ __align__(16) u16 Ps[64 * 72];   // [q][key] granule-rotated

    const int t = threadIdx.x;
    const int lane = t & 63;
    const int w = t >> 6;
    const int l16 = lane & 15, quad = lane >> 4;
    const int a7 = l16 & 7;

    const int id   = blockIdx.x;
    const int xcd  = id & 7;
    const int qt   = (id >> 3) & 7;
    const int panel = xcd + ((id >> 6) << 3);   // 0..255
    const int h = panel & 15;
    const int b = panel >> 4;
    const int qrow0 = b * 512 + qt * 64;
    const int krow_base = b * 512;

    // Q fragments straight to registers: wave w owns q rows w*16..w*16+15.
    bf16x8 aq[4];
    {
        const u16* qrow = q_src + (size_t)(qrow0 + w * 16 + l16) * 2048;
#pragma unroll
        for (int ks = 0; ks < 4; ++ks) {
            int col = ks * 32 + quad * 8;
            const u16* src = (col < 64) ? qrow + h * 64 + col
                                        : qrow + 1024 + h * 64 + (col - 64);
            aq[ks] = *(const bf16x8*)src;
        }
    }

    // --- staging geometry (kt-independent) ---
    const int colK = (t & 15) * 8;            // K column chunk (u16)
    const int r0k  = t >> 4;                  // K row 0..15 (+16p)
    const u16* kbase; int kstr;
    if (colK < 64) { kbase = kv_src + h * 64 + colK;        kstr = 2048; }
    else           { kbase = kr_src + 1024 + (colK - 64);   kstr = 1088; }
    u16* kw = &Ks[r0k * 136 + colK];

    const int v00 = (t & 7) * 8;              // vd chunk
    const int r0v = t >> 3;                   // key row 0..31 (+32p)
    const u16* vbase = kv_src + 1024 + h * 64 + v00;
    const int rotA = (r0v + v00) & 63;
    const int rotB = (r0v + 32 + v00) & 63;
    u16* vwA = &Vt[v00 * 72 + rotA];
    u16* vwB = &Vt[v00 * 72 + rotB];

    auto LOADT = [&](int krow0, uint4& K0, uint4& K1, uint4& K2, uint4& K3,
                     uint4& V0, uint4& V1) {
        K0 = *(const uint4*)(kbase + (size_t)(krow0 + r0k     ) * kstr);
        K1 = *(const uint4*)(kbase + (size_t)(krow0 + r0k + 16) * kstr);
        K2 = *(const uint4*)(kbase + (size_t)(krow0 + r0k + 32) * kstr);
        K3 = *(const uint4*)(kbase + (size_t)(krow0 + r0k + 48) * kstr);
        V0 = *(const uint4*)(vbase + (size_t)(krow0 + r0v     ) * 2048);
        V1 = *(const uint4*)(vbase + (size_t)(krow0 + r0v + 32) * 2048);
    };
    auto WRITET = [&](const uint4& K0, const uint4& K1, const uint4& K2, const uint4& K3,
                      const uint4& V0, const uint4& V1) {
        *(uint4*)(kw)            = K0;
        *(uint4*)(kw + 16 * 136) = K1;
        *(uint4*)(kw + 32 * 136) = K2;
        *(uint4*)(kw + 48 * 136) = K3;
        u16 ta[8], tb[8];
        __builtin_memcpy(ta, &V0, 16);
        __builtin_memcpy(tb, &V1, 16);
#pragma unroll
        for (int j2 = 0; j2 < 8; ++j2) { vwA[j2 * 72] = ta[j2]; vwB[j2 * 72] = tb[j2]; }
    };

    float m2 = -1e30f, l_run = 0.f;           // per-lane: q-row l16 (log2 dom.)
    f32x4 o[4];
#pragma unroll
    for (int n = 0; n < 4; ++n) o[n] = (f32x4){0.f, 0.f, 0.f, 0.f};

    const float C = 0.10411756f;              // log2(e)/sqrt(192)

    uint4 kA0, kA1, kA2, kA3, vA0, vA1;
    uint4 kB0, kB1, kB2, kB3, vB0, vB1;
    LOADT(krow_base, kA0, kA1, kA2, kA3, vA0, vA1);   // kt = 0

    for (int kt = 0; kt < 8; ++kt) {
        // (A) all waves done reading Ks/Vt of previous tile
        __builtin_amdgcn_s_barrier();
        if ((kt & 1) == 0) {
            WRITET(kA0, kA1, kA2, kA3, vA0, vA1);
            if (kt < 7) LOADT(krow_base + (kt + 1) * 64, kB0, kB1, kB2, kB3, vB0, vB1);
        } else {
            WRITET(kB0, kB1, kB2, kB3, vB0, vB1);
            if (kt < 7) LOADT(krow_base + (kt + 1) * 64, kA0, kA1, kA2, kA3, vA0, vA1);
        }
        asm volatile("s_waitcnt lgkmcnt(0)");     // my ds_writes visible
        __builtin_amdgcn_sched_barrier(0);
        // (B) everyone's ds_writes visible; vmcnt NOT drained -> prefetch flies
        __builtin_amdgcn_s_barrier();

        // S strip, SWAPPED: s[n] = K_n Q^T -> lane holds S[key=16n+4q+r][q=l16]
        f32x4 s[4];
#pragma unroll
        for (int n = 0; n < 4; ++n) s[n] = (f32x4){0.f, 0.f, 0.f, 0.f};
#pragma unroll
        for (int ks = 0; ks < 4; ++ks) {
#pragma unroll
            for (int n = 0; n < 4; ++n) {
                bf16x8 bk = *(const bf16x8*)&Ks[(n * 16 + l16) * 136 + ks * 32 + quad * 8];
                s[n] = __builtin_amdgcn_mfma_f32_16x16x32_bf16(bk, aq[ks], s[n], 0, 0, 0);
            }
        }

        // online softmax (log2 domain), row = q = l16 per lane
        float mx = fmaxf(fmaxf(s[0][0], s[0][1]), fmaxf(s[0][2], s[0][3]));
#pragma unroll
        for (int n = 1; n < 4; ++n)
            mx = fmaxf(mx, fmaxf(fmaxf(s[n][0], s[n][1]), fmaxf(s[n][2], s[n][3])));
        mx = fmaxf(mx, __shfl_xor(mx, 16));
        mx = fmaxf(mx, __shfl_xor(mx, 32));

        float mnew = fmaxf(m2, mx * C);
        float alpha = __builtin_amdgcn_exp2f(m2 - mnew);
        m2 = mnew;
        float rs = 0.f;
#pragma unroll
        for (int n = 0; n < 4; ++n)
#pragma unroll
            for (int r = 0; r < 4; ++r) {
                float pv = __builtin_amdgcn_exp2f(__builtin_fmaf(s[n][r], C, -mnew));
                s[n][r] = pv;
                rs += pv;
            }
        rs += __shfl_xor(rs, 16);
        rs += __shfl_xor(rs, 32);
        l_run = l_run * alpha + rs;

        // redistribute alpha to o-layout rows (q = quad*4+r lives at lane q<16)
        float aO[4];
#pragma unroll
        for (int r = 0; r < 4; ++r) aO[r] = __shfl(alpha, quad * 4 + r);
#pragma unroll
        for (int n = 0; n < 4; ++n)
#pragma unroll
            for (int r = 0; r < 4; ++r) o[n][r] *= aO[r];

        // P -> LDS: row q=w*16+l16 (wave-private); logical cols cb=n*16+quad*4,
        // granule g=cb>>3=2n+(quad>>1), half ql=quad&1.  Physical granule
        // p=(g+a7)&7 (rotation).  One b64 store per n, conflict-free.
        {
            u16* prow = &Ps[(w * 16 + l16) * 72];
#pragma unroll
            for (int n = 0; n < 4; ++n) {
                int p = (2 * n + (quad >> 1) + a7) & 7;
                u32 p0 = (u32)f2bf(s[n][0]) | ((u32)f2bf(s[n][1]) << 16);
                u32 p1 = (u32)f2bf(s[n][2]) | ((u32)f2bf(s[n][3]) << 16);
                uint2 pp = { p0, p1 };
                *(uint2*)&prow[p * 8 + (quad & 1) * 4] = pp;
            }
        }

        // O += P @ V; Ps read undoes the granule rotation (g = 4kk+quad)
#pragma unroll
        for (int kk = 0; kk < 2; ++kk) {
            bf16x8 ap = *(const bf16x8*)&Ps[(w * 16 + l16) * 72
                          + (((4 * kk + quad + a7) & 7) << 3)];
#pragma unroll
            for (int n = 0; n < 4; ++n) {
                bf16x8 bv = *(const bf16x8*)&Vt[(n * 16 + l16) * 72
                              + ((kk * 32 + quad * 8 + n * 16 + (l16 & 8)) & 63)];
                o[n] = __builtin_amdgcn_mfma_f32_16x16x32_bf16(ap, bv, o[n], 0, 0, 0);
            }
        }
    }

    // epilogue: inv(l_run) lives at lane q (<16); o rows are quad*4+r
    float inv = 1.0f / l_run;
#pragma unroll
    for (int r = 0; r < 4; ++r) {
        float invO = __shfl(inv, quad * 4 + r);
        int row = qrow0 + w * 16 + quad * 4 + r;
#pragma unroll
        for (int n = 0; n < 4; ++n) {
            int col = h * 64 + n * 16 + l16;
            o_dst[(size_t)row * ldo + col] = f2bf(o[n][r] * invO);
        }
    }
}

// ---------------------------------------------------------------------------
extern "C" void kernel_launch(void* const* d_in, const int* in_sizes, int n_in,
                              void* d_out, int out_size, void* d_ws, size_t ws_size,
                              hipStream_t stream)
{
    const float* h    = (const float*)d_in[0];
    const float* Wdkv = (const float*)d_in[1];
    const float* bdkv = (const float*)d_in[2];
    const float* Wuk  = (const float*)d_in[3];
    const float* buk  = (const float*)d_in[4];
    const float* Wuv  = (const float*)d_in[5];
    const float* buv  = (const float*)d_in[6];
    const float* Wdq  = (const float*)d_in[7];
    const float* bdq  = (const float*)d_in[8];
    const float* Wuq  = (const float*)d_in[9];
    const float* buq  = (const float*)d_in[10];
    const float* Wqr  = (const float*)d_in[11];
    const float* bqr  = (const float*)d_in[12];
    const float* Wkr  = (const float*)d_in[13];
    const float* bkr  = (const float*)d_in[14];
    const float* Wfc  = (const float*)d_in[15];
    const float* bfc  = (const float*)d_in[16];

    // Workspace layout (98,062,592 B total):
    //   out1      : 8192 x 1088 bf16  [c_kv | c_q | k_r]; attn out -> cols 0..1023
    //   out2a/hbf : 8192 x 2048 bf16  (h-bf16 during stage 1; [k_c|v_c] after)
    //   out2b     : 8192 x 2048 bf16  [q_c | q_r]
    //   w1        : 1152 x 2048 bf16  [Wdkv;Wdq;Wkr;zero-pad]
    //   w2a,w2b   : 2048 x 512 bf16   [Wuk;Wuv], [Wuq;Wqr]
    //   wfc       : 2048 x 1024 bf16
    //   bias_s1   : 1088 fp32 [bdkv|bdq|bkr];  bias_2: 4096 fp32 [buk|buv|buq|bqr]
    char* ws = (char*)d_ws;
    u16* out1   = (u16*)ws;                              // 17,825,792 B
    u16* hbf    = (u16*)(ws + 17825792);                 // 33,554,432 B (= out2a)
    u16* out2a  = hbf;
    u16* out2b  = (u16*)(ws + 51380224);                 // 33,554,432 B
    u16* w1     = (u16*)(ws + 84934656);                 //  4,718,592 B
    u16* w2a    = (u16*)(ws + 89653248);                 //  2,097,152 B
    u16* w2b    = (u16*)(ws + 91750400);                 //  2,097,152 B
    u16* wfc    = (u16*)(ws + 93847552);                 //  4,194,304 B
    float* bias_s1 = (float*)(ws + 98041856);            //      4,352 B
    float* bias_2  = (float*)(ws + 98046208);            //     16,384 B

    // --- conversion pass: h + all weights -> bf16 (8-elem chunks) ---
    Cvt9 cd;
    const float* srcs[9] = { h, Wdkv, Wdq, Wkr, Wuk, Wuv, Wuq, Wqr, Wfc };
    u16* dsts[9] = { hbf, w1, w1 + 512 * 2048, w1 + 1024 * 2048,
                     w2a, w2a + 1024 * 512, w2b, w2b + 1024 * 512, wfc };
    int cnts[9] = { 2097152, 131072, 131072, 16384, 65536, 65536, 65536, 65536, 262144 };
    int acc2 = 0;
    for (int i = 0; i < 9; ++i) { cd.src[i] = srcs[i]; cd.dst[i] = dsts[i]; acc2 += cnts[i]; cd.end[i] = acc2; }
    cvt_all<<<(acc2 + 255) / 256, 256, 0, stream>>>(cd, acc2);
    // zero-pad w1 rows 1088..1151
    hipMemsetAsync(w1 + 1088 * 2048, 0, 64 * 2048 * sizeof(u16), stream);

    // --- bias concat (fp32) ---
    Cpy7 bc;
    const float* bs[7] = { bdkv, bdq, bkr, buk, buv, buq, bqr };
    float* bd[7] = { bias_s1, bias_s1 + 512, bias_s1 + 1024,
                     bias_2, bias_2 + 1024, bias_2 + 2048, bias_2 + 3072 };
    int bn[7] = { 512, 512, 64, 1024, 1024, 1024, 1024 };
    int bacc = 0;
    for (int i = 0; i < 7; ++i) { bc.src[i] = bs[i]; bc.dst[i] = bd[i]; bacc += bn[i]; bc.end[i] = bacc; }
    copy_f32<<<(bacc + 255) / 256, 256, 0, stream>>>(bc, bacc);

    // --- stage 1: [c_kv|c_q|k_r] = hbf @ w1^T, N=1088, K=2048 ---
    gemm_v6<false><<<dim3(64, 9), 256, 0, stream>>>(
        hbf, w1, out1, bias_s1,
        hbf, w1, out1, bias_s1, 9, 2048, 2048, 1088, 1088, 2048);
    rope_inplace<<<1024, 256, 0, stream>>>(out1, 1088, 1024, 32, 8192 * 32);   // k_r

    // --- stage 2 (fused 2a+2b): K=512, N=2048 each half ---
    gemm_v6<false><<<dim3(64, 32), 256, 0, stream>>>(
        out1,       w2a, out2a, bias_2,
        out1 + 512, w2b, out2b, bias_2 + 2048, 16, 1088, 512, 2048, 2048, 512);
    rope_inplace<<<16384, 256, 0, stream>>>(out2b, 2048, 1024, 512, 8192 * 512);  // q_r

    // --- attention: 1-D grid, temporal XCD swizzle inside the kernel ---
    attn_kernel<<<2048, 256, 0, stream>>>(out2b, out2a, out1, out1, 1088);

    // --- final projection: d_out = attn @ wfc^T, fp32 out ---
    gemm_v6<true><<<dim3(64, 16), 256, 0, stream>>>(
        out1, wfc, d_out, bfc,
        out1, wfc, d_out, bfc, 16, 1088, 1024, 2048, 2048, 1024);
}